// Round 2
// baseline (533.156 us; speedup 1.0000x reference)
//
#include <hip/hip_runtime.h>

// ArDCA loss: loss = -sum_{m,i} W[m] * log_softmax(h[i,:] + sum_{j<i} J[i,j,:,X[m,j]])[X[m,i]]
//             + 1e-6 * sum h^2 + 1e-4 * sum_{j<i} J^2
// M=8192, L=256, Q=21. Output: single fp32 scalar.
//
// R6 = R5 resubmitted verbatim (R5 bench died in container acquire — infra
// flake, no kernel signal). fp8-e4m3 LDS staging:
//  - Rows staged as 21x e4m3 + 3 pad = 24 B (was 48 B f16). Encode with HW
//    v_cvt_pk_fp8_f32 on J*256 (dodges the e4m3 denormal cliff: raw |J|~0.01
//    is below the 2^-6 min normal; scaled values ~[0.015, 14] are normal).
//    Decode with v_cvt_pk_f32_fp8, epilogue multiplies acc by 1/256.
//  - Gather = 3x ds_read_b64 at 24-B row stride. Bank-pair class = 3b mod 16
//    (gcd(3,16)=1): 21 rows -> max 2 distinct addrs per bank = conflict-FREE
//    (2-way aliasing is the free wave64 baseline). Was: 48-B rows -> 8
//    bank-quad classes, pigeonhole 3-way, 1.43x measured conflict tax.
//  - Accumulate in f32x2 (v_pk_add_f32): 11 pk-adds/j, and removes the old
//    f16 accumulation rounding error (offsets fp8 quantization error).
//  - Fallback if accuracy fails: f16 rows at 56-B stride (7b mod 16, also
//    conflict-free), ~310 us expected.
//
// Carried from R4: reg terms ride the blockIdx.x==0 staging (J^2 from the
// fp32 values pre-encode, h^2 in the epilogue).

#define M_SEQ 8192
#define L_POS 256
#define Q_SYM 21
#define QQ    441
#define JC    16
#define NROWS (JC * Q_SYM)       // 336 rows per chunk; 336*24 B = 8064 B LDS

typedef float f32x2 __attribute__((ext_vector_type(2)));

__device__ __forceinline__ float wave_block_reduce(float v, float* red, int tid) {
    #pragma unroll
    for (int off = 32; off > 0; off >>= 1) v += __shfl_down(v, off, 64);
    if ((tid & 63) == 0) red[tid >> 6] = v;
    __syncthreads();
    return red[0] + red[1] + red[2] + red[3];
}

__global__ void zero_out(float* __restrict__ out) { out[0] = 0.0f; }

// Encode one row: 21 strided fp32 J values -> 24 B of e4m3(J*256) in LDS.
// rs returns sum of squares of the raw values (for the J^2 reg term).
__device__ __forceinline__ void stage_row(const float* __restrict__ s,
                                          uint2* __restrict__ dst,
                                          bool add_reg, float& regsum) {
    const float S = 256.0f;
    unsigned int d[6];
    float rs = 0.0f;
    #pragma unroll
    for (int g = 0; g < 5; ++g) {
        float a0 = s[(4 * g + 0) * Q_SYM];
        float a1 = s[(4 * g + 1) * Q_SYM];
        float a2 = s[(4 * g + 2) * Q_SYM];
        float a3 = s[(4 * g + 3) * Q_SYM];
        rs += a0 * a0 + a1 * a1 + a2 * a2 + a3 * a3;
        int t = __builtin_amdgcn_cvt_pk_fp8_f32(a0 * S, a1 * S, 0, false);
        t     = __builtin_amdgcn_cvt_pk_fp8_f32(a2 * S, a3 * S, t, true);
        d[g] = (unsigned int)t;
    }
    float a20 = s[20 * Q_SYM];
    rs += a20 * a20;
    d[5] = (unsigned int)__builtin_amdgcn_cvt_pk_fp8_f32(a20 * S, 0.0f, 0, false);
    if (add_reg) regsum += rs;
    dst[0] = make_uint2(d[0], d[1]);
    dst[1] = make_uint2(d[2], d[3]);
    dst[2] = make_uint2(d[4], d[5]);
}

// One block per (m-chunk of 256, i). Each thread owns one m.
__global__ __launch_bounds__(256, 8) void pair_nll_kernel(const int* __restrict__ X,
                                                          const float* __restrict__ W,
                                                          const float* __restrict__ h,
                                                          const float* __restrict__ J,
                                                          float* __restrict__ out) {
    __shared__ uint2 JL[NROWS * 3];      // 336 rows * 24 B = 8064 B
    __shared__ float red[4];

    const int tid = threadIdx.x;
    const int i  = blockIdx.y;
    const int m  = blockIdx.x * 256 + tid;
    const bool do_reg = (blockIdx.x == 0);
    const int* xrow = X + (size_t)m * L_POS;

    // thread-owned staging rows (fixed for whole kernel)
    const int row0 = tid;                       // 0..255
    const int jc0  = row0 / Q_SYM;
    const int b0   = row0 - jc0 * Q_SYM;
    const int row1 = tid + 256;                 // 256..335 valid when tid < 80
    const int jc1  = row1 / Q_SYM;
    const int b1   = row1 - jc1 * Q_SYM;
    const bool has_row1 = (row1 < NROWS);

    f32x2 acc[11];
    #pragma unroll
    for (int k = 0; k < 11; ++k) { acc[k].x = 0.0f; acc[k].y = 0.0f; }
    float regsum = 0.0f;   // sum of J^2 over this thread's staged (i, j<i, :, b) values

    for (int j0 = 0; j0 < i; j0 += JC) {
        const float* Jsrc = J + ((size_t)i * L_POS + j0) * QQ;
        __syncthreads();   // protect previous chunk's LDS reads

        // ---- stage: each thread encodes its row(s); 3 ds_write_b64 each
        stage_row(Jsrc + jc0 * QQ + b0, JL + row0 * 3,
                  do_reg && (j0 + jc0 < i), regsum);
        if (has_row1) {
            stage_row(Jsrc + jc1 * QQ + b1, JL + row1 * 3,
                      do_reg && (j0 + jc1 < i), regsum);
        }
        __syncthreads();

        // ---- this thread's 16 X values (row-contiguous, vectorized)
        int4 xa = *(const int4*)(xrow + j0);
        int4 xb = *(const int4*)(xrow + j0 + 4);
        int4 xc = *(const int4*)(xrow + j0 + 8);
        int4 xd = *(const int4*)(xrow + j0 + 12);
        int xv[JC] = {xa.x, xa.y, xa.z, xa.w, xb.x, xb.y, xb.z, xb.w,
                      xc.x, xc.y, xc.z, xc.w, xd.x, xd.y, xd.z, xd.w};

        #pragma unroll
        for (int jc = 0; jc < JC; ++jc) {
            if (j0 + jc < i) {   // block-uniform guard (scalar branch)
                int b = xv[jc];
                const uint2* r = JL + (jc * Q_SYM + b) * 3;
                uint2 q0 = r[0];
                uint2 q1 = r[1];
                uint2 q2 = r[2];
                acc[0]  += __builtin_amdgcn_cvt_pk_f32_fp8((int)q0.x, false);
                acc[1]  += __builtin_amdgcn_cvt_pk_f32_fp8((int)q0.x, true);
                acc[2]  += __builtin_amdgcn_cvt_pk_f32_fp8((int)q0.y, false);
                acc[3]  += __builtin_amdgcn_cvt_pk_f32_fp8((int)q0.y, true);
                acc[4]  += __builtin_amdgcn_cvt_pk_f32_fp8((int)q1.x, false);
                acc[5]  += __builtin_amdgcn_cvt_pk_f32_fp8((int)q1.x, true);
                acc[6]  += __builtin_amdgcn_cvt_pk_f32_fp8((int)q1.y, false);
                acc[7]  += __builtin_amdgcn_cvt_pk_f32_fp8((int)q1.y, true);
                acc[8]  += __builtin_amdgcn_cvt_pk_f32_fp8((int)q2.x, false);
                acc[9]  += __builtin_amdgcn_cvt_pk_f32_fp8((int)q2.x, true);
                acc[10] += __builtin_amdgcn_cvt_pk_f32_fp8((int)q2.y, false);
            }
        }
    }

    // ---- logits = h[i,:] + pair/256 ; log-softmax ; pick gold = X[m,i]
    const float* hrow = h + i * Q_SYM;
    const float INV = 0.00390625f;   // 1/256: undo the fp8 encode pre-scale
    float logits[Q_SYM];
    #pragma unroll
    for (int k = 0; k < 10; ++k) {
        logits[2 * k]     = hrow[2 * k]     + acc[k].x * INV;
        logits[2 * k + 1] = hrow[2 * k + 1] + acc[k].y * INV;
    }
    logits[20] = hrow[20] + acc[10].x * INV;

    float mx = -3.4e38f;
    #pragma unroll
    for (int a = 0; a < Q_SYM; ++a) mx = fmaxf(mx, logits[a]);
    float s = 0.0f;
    #pragma unroll
    for (int a = 0; a < Q_SYM; ++a) s += __expf(logits[a] - mx);
    int g = xrow[i];
    float gold = 0.0f;
    #pragma unroll
    for (int a = 0; a < Q_SYM; ++a) gold = (a == g) ? logits[a] : gold;
    float logp = gold - mx - __logf(s);
    float v = -W[m] * logp;

    // ---- fold regularization terms (blockIdx.x==0 blocks only)
    if (do_reg) {
        v += 1e-4f * regsum;
        if (tid < Q_SYM) {
            float hv = hrow[tid];
            v += 1e-6f * hv * hv;
        }
    }

    __syncthreads();   // LDS reuse safety before reduction
    float tot = wave_block_reduce(v, red, tid);
    if (tid == 0) atomicAdd(out, tot);
}

extern "C" void kernel_launch(void* const* d_in, const int* in_sizes, int n_in,
                              void* d_out, int out_size, void* d_ws, size_t ws_size,
                              hipStream_t stream) {
    const int*   X = (const int*)d_in[0];
    const float* W = (const float*)d_in[1];
    const float* h = (const float*)d_in[2];
    const float* J = (const float*)d_in[3];
    float* out = (float*)d_out;

    hipLaunchKernelGGL(zero_out, dim3(1), dim3(1), 0, stream, out);
    dim3 grid(M_SEQ / 256, L_POS);
    hipLaunchKernelGGL(pair_nll_kernel, grid, dim3(256), 0, stream, X, W, h, J, out);
}